// Round 4
// baseline (195.471 us; speedup 1.0000x reference)
//
#include <hip/hip_runtime.h>
#include <math.h>

#define B 2
#define C 32
#define H 128
#define W 416
#define D 48
#define HW (H*W)
#define CHW (C*HW)
#define EPSN 1e-3f
#define ISCALE 0.05892556509887896f   // 1/sqrt(C*9)
#define ESTR 36     // k_e LDS stride (floats): 16B-aligned pad, unswizzled
#define LSTR 32     // k_lr LDS stride: 128B columns + XOR swizzle
#define DSPE 24     // k_e disparities per z-block (z=2)
#define DSPL 16     // k_lr disparities per z-block (z=3)
#define NZ 3

__device__ __forceinline__ float clip10(float x) {
    return fminf(fmaxf(x, -10.0f), 10.0f);
}

#define FMA4(acc, f, k, u) acc += f[4*(k)+0]*(u).x + f[4*(k)+1]*(u).y \
                               + f[4*(k)+2]*(u).z + f[4*(k)+3]*(u).w;

// ---------------------------------------------------------------------------
// k_norm: 3x3 zero-padded box of sql/sqr -> inverse patch norms inl/inr.
__global__ __launch_bounds__(256) void k_norm(const float* __restrict__ sql,
                                              const float* __restrict__ sqr,
                                              float* __restrict__ inl,
                                              float* __restrict__ inr) {
    int idx = blockIdx.x * 256 + threadIdx.x;
    if (idx >= B * HW) return;
    int b = idx / HW, hw = idx - b * HW;
    int h = hw / W, w = hw - h * W;
    float sl = 0.f, sr = 0.f;
#pragma unroll
    for (int di = -1; di <= 1; ++di) {
        int hh = h + di;
        if (hh < 0 || hh >= H) continue;
#pragma unroll
        for (int dj = -1; dj <= 1; ++dj) {
            int ww = w + dj;
            if (ww < 0 || ww >= W) continue;
            int p = b * HW + hh * W + ww;
            sl += sql[p];
            sr += sqr[p];
        }
    }
    inl[idx] = 1.0f / fmaxf(sqrtf(sl), EPSN);
    inr[idx] = 1.0f / fmaxf(sqrtf(sr), EPSN);
}

// ---------------------------------------------------------------------------
// stage_row_v2 (k_e): stage [C][W] row into LDS transposed [w][c], stride
// ESTR=36. Stride-1 column reads are conflict-free: bank-quad=(9v+q)%8.
__device__ __forceinline__ void stage_row_v2(const float* __restrict__ gsrc,
                                             float* __restrict__ lds,
                                             int tid, int nthreads) {
    for (int t = tid; t < (W / 4) * C; t += nthreads) {
        int rw = t & 7;
        int cl = (t >> 3) & 7;
        int g  = t >> 6;              // 0..51
        int wg = g % 13;
        int ch = g / 13;              // 0..3
        int c  = ch * 8 + cl;
        int w4 = (wg * 8 + rw) * 4;
        float4 v = *(const float4*)(gsrc + (size_t)c * HW + w4);
        lds[(w4 + 0) * ESTR + c] = v.x;
        lds[(w4 + 1) * ESTR + c] = v.y;
        lds[(w4 + 2) * ESTR + c] = v.z;
        lds[(w4 + 3) * ESTR + c] = v.w;
    }
}

// ---------------------------------------------------------------------------
// stage_row3_swz (k_lr): stage VERTICAL 3-tap vsum[c,w] (zero-pad in h) into
// 128B-stride swizzled LDS: channel-group g2 of column v -> float4 slot
// g2 ^ ((v>>1)&7). Reads (v=v0+2*lane): bank-quad = q^key spans all 8 quads,
// 8 lanes each = conflict-free. Writes: bank = 4*slot+wd -> all 32 banks,
// 2-way per instr = free.
__device__ __forceinline__ void stage_row3_swz(const float* __restrict__ gsrc,
                                               float* __restrict__ lds,
                                               int h, int tid, int nthreads) {
    for (int t = tid; t < (W / 4) * C; t += nthreads) {
        int rw = t & 7;
        int cl = (t >> 3) & 7;
        int g  = t >> 6;
        int wg = g % 13;
        int ch = g / 13;
        int c  = ch * 8 + cl;
        int w4 = (wg * 8 + rw) * 4;
        const float* p = gsrc + (size_t)c * HW + w4;
        float4 v = *(const float4*)(p);
        if (h > 0) {
            float4 a = *(const float4*)(p - W);
            v.x += a.x; v.y += a.y; v.z += a.z; v.w += a.w;
        }
        if (h < H - 1) {
            float4 a = *(const float4*)(p + W);
            v.x += a.x; v.y += a.y; v.z += a.z; v.w += a.w;
        }
        int g2 = c >> 2, wd = c & 3;
        int k0 = (w4 >> 1) & 7;        // key for v=w4, w4+1
        int k1 = (k0 + 1) & 7;         // key for v=w4+2, w4+3
        lds[(w4 + 0) * LSTR + 4 * (g2 ^ k0) + wd] = v.x;
        lds[(w4 + 1) * LSTR + 4 * (g2 ^ k0) + wd] = v.y;
        lds[(w4 + 2) * LSTR + 4 * (g2 ^ k1) + wd] = v.z;
        lds[(w4 + 3) * LSTR + 4 * (g2 ^ k1) + wd] = v.w;
    }
}

// ---------------------------------------------------------------------------
// dot32e (k_e): 8 b128 loads issued up front, 2 independent FMA chains.
__device__ __forceinline__ float dot32e(const float* __restrict__ x,
                                        const float* __restrict__ col) {
    const float4* c4 = (const float4*)col;
    float4 u0 = c4[0], u1 = c4[1], u2 = c4[2], u3 = c4[3];
    float4 u4 = c4[4], u5 = c4[5], u6 = c4[6], u7 = c4[7];
    float a = 0.f, b = 0.f;
    FMA4(a, x, 0, u0) FMA4(a, x, 1, u1) FMA4(a, x, 2, u2) FMA4(a, x, 3, u3)
    FMA4(b, x, 4, u4) FMA4(b, x, 5, u5) FMA4(b, x, 6, u6) FMA4(b, x, 7, u7)
    return a + b;
}

// dot2s (k_lr): swizzled column read (slot q^ky holds channels 4q..4q+3),
// two dots (w, w+1), 2 chains each.
__device__ __forceinline__ void dot2s(const float* __restrict__ fl0,
                                      const float* __restrict__ fl1,
                                      const float4* __restrict__ c4, int ky,
                                      float& a0, float& a1) {
    float4 u0 = c4[ky],     u1 = c4[1 ^ ky], u2 = c4[2 ^ ky], u3 = c4[3 ^ ky];
    float4 u4 = c4[4 ^ ky], u5 = c4[5 ^ ky], u6 = c4[6 ^ ky], u7 = c4[7 ^ ky];
    float x0 = 0.f, x1 = 0.f, y0 = 0.f, y1 = 0.f;
    FMA4(x0, fl0, 0, u0) FMA4(x0, fl0, 1, u1) FMA4(x0, fl0, 2, u2) FMA4(x0, fl0, 3, u3)
    FMA4(x1, fl0, 4, u4) FMA4(x1, fl0, 5, u5) FMA4(x1, fl0, 6, u6) FMA4(x1, fl0, 7, u7)
    FMA4(y0, fl1, 0, u0) FMA4(y0, fl1, 1, u1) FMA4(y0, fl1, 2, u2) FMA4(y0, fl1, 3, u3)
    FMA4(y1, fl1, 4, u4) FMA4(y1, fl1, 5, u5) FMA4(y1, fl1, 6, u6) FMA4(y1, fl1, 7, u7)
    a0 = x0 + x1; a1 = y0 + y1;
}

// ---------------------------------------------------------------------------
// k_lr: sL and sR. Grid (NZ*H, B), z fastest (same-h triplets adjacent for
// L2 reuse of staging rows). 256 threads; thread owns (w,w+1)=(2tid,2tid+1)
// and all DSPL=16 d's of its z-block. 53KB swizzled LDS -> 3 blocks/CU,
// __launch_bounds__(256,3) keeps VGPR <= 170 for 3 waves/SIMD.
// Rolling 3-tap of column dots g(v); inm inline; in* scale reg-prefetched.
__global__ __launch_bounds__(256, 3) void k_lr(const float* __restrict__ xm,
                                               const float* __restrict__ xl,
                                               const float* __restrict__ xr,
                                               const float* __restrict__ inl,
                                               const float* __restrict__ inr,
                                               float* __restrict__ out) {
    __shared__ float sB[W * LSTR];    // 53248 B
    int tid = threadIdx.x;
    int bx = blockIdx.x;
    int z = bx % NZ;
    int h = bx / NZ;
    int b = blockIdx.y;
    int d0 = z * DSPL;
    bool act = tid < (W / 2);         // 208 active
    int w = 2 * tid;
    int bhw = b * HW + h * W;
    const float* pm = xm + (size_t)b * CHW + h * W;

    float fl0[C], fl1[C];
    if (act) {
        float am0 = 0.f, am1 = 0.f;
#pragma unroll
        for (int c = 0; c < C; ++c) {
            float2 mv = *(const float2*)(pm + (size_t)c * HW + w);
            fl0[c] = mv.x; fl1[c] = mv.y;
            am0 += mv.x * mv.x; am1 += mv.y * mv.y;
        }
        float im0 = 1.0f / fmaxf(sqrtf(am0), EPSN);
        float im1 = 1.0f / fmaxf(sqrtf(am1), EPSN);
#pragma unroll
        for (int c = 0; c < C; ++c) { fl0[c] *= im0; fl1[c] *= im1; }
    }

    // ---- phase L: columns v = w+d0-1+j, j=0..DSPL+2. Center m=v-1 done at
    // j>=2; store pairs (s0 from j-1, s1 from j) at j>=3 for d = d0+j-3.
    stage_row3_swz(xl + (size_t)b * CHW + h * W, sB, h, tid, 256);
    __syncthreads();
    if (act) {
        float* o = out + ((size_t)b * 3 + 0) * D * HW + h * W;
        const float* inx = inl + bhw;
        float g0a = 0.f, g0b = 0.f, g1a = 0.f, g1b = 0.f, s0p = 0.f;
        float scn = 0.f;
        for (int j = 0; j <= DSPL + 2; ++j) {
            int v = w + d0 - 1 + j;
            bool ok = (v >= 0) && (v < W);
            int vc = ok ? v : 0;
            float c0, c1;
            dot2s(fl0, fl1, (const float4*)(sB + vc * LSTR), (vc >> 1) & 7, c0, c1);
            c0 = ok ? c0 : 0.f;
            c1 = ok ? c1 : 0.f;
            float sc = scn;                       // inx[m(j)], prefetched
            int mn = w + d0 + j - 1;              // m(j+1)
            scn = (mn >= 0 && mn < W) ? inx[mn] : 0.f;
            float s0 = 0.f, s1 = 0.f;
            if (j >= 2) {
                int m = v - 1;
                if (m < W) {
                    float s = sc * ISCALE;
                    s0 = clip10((g0a + g0b + c0) * s);
                    s1 = clip10((g1a + g1b + c1) * s);
                }
                if (j >= 3) {
                    int d = d0 + j - 3;
                    *(float2*)(o + (size_t)d * HW + w) = make_float2(s0p, s1);
                }
            }
            s0p = s0;
            g0a = g0b; g0b = c0;
            g1a = g1b; g1b = c1;
        }
    }
    __syncthreads();

    // ---- phase R: columns v = w-d0-DSPL+j, j=0..DSPL+2, ascending. Center
    // m=v-1 at j>=2; store pairs at j>=3 for d = d0+DSPL+2-j.
    stage_row3_swz(xr + (size_t)b * CHW + h * W, sB, h, tid, 256);
    __syncthreads();
    if (act) {
        float* o = out + ((size_t)b * 3 + 1) * D * HW + h * W;
        const float* inx = inr + bhw;
        float g0a = 0.f, g0b = 0.f, g1a = 0.f, g1b = 0.f, s0p = 0.f;
        float scn = 0.f;
        for (int j = 0; j <= DSPL + 2; ++j) {
            int v = w - d0 - DSPL + j;
            bool ok = (v >= 0) && (v < W);
            int vc = ok ? v : 0;
            float c0, c1;
            dot2s(fl0, fl1, (const float4*)(sB + vc * LSTR), (vc >> 1) & 7, c0, c1);
            c0 = ok ? c0 : 0.f;
            c1 = ok ? c1 : 0.f;
            float sc = scn;                       // inx[m(j)], prefetched
            int mn = w - d0 - DSPL + j;           // m(j+1) = v(j)  (m<W always)
            scn = (mn >= 0) ? inx[mn] : 0.f;
            float s0 = 0.f, s1 = 0.f;
            if (j >= 2) {
                int m = v - 1;
                if (m >= 0) {
                    float s = sc * ISCALE;
                    s0 = clip10((g0a + g0b + c0) * s);
                    s1 = clip10((g1a + g1b + c1) * s);
                }
                if (j >= 3) {
                    int d = d0 + DSPL + 2 - j;
                    *(float2*)(o + (size_t)d * HW + w) = make_float2(s0p, s1);
                }
            }
            s0p = s0;
            g0a = g0b; g0b = c0;
            g1a = g1b; g1b = c1;
        }
    }
}

// ---------------------------------------------------------------------------
// k_e: EH[b,d,h,v] = horizontal 3-tap of E, E[v] = sum_c xl[.,v+2d]*xr[.,v].
// Round-1 structure (known-good): 448 thr, wave-halo v = wave*62+lane-1,
// 62 sums emitted via shuffles; z splits d in two. dc==0 also emits sql/sqr.
__global__ __launch_bounds__(448) void k_e(const float* __restrict__ xl,
                                           const float* __restrict__ xr,
                                           float* __restrict__ EH,
                                           float* __restrict__ sql,
                                           float* __restrict__ sqr) {
    __shared__ float sXL[W * ESTR];   // 59904 B
    int tid = threadIdx.x;
    int h = blockIdx.x;
    int b = blockIdx.y;
    int d0 = blockIdx.z * DSPE;
    int lane = tid & 63;
    int wv = tid >> 6;                // 0..6
    int v = wv * 62 + lane - 1;       // -1 .. 433
    bool vin = (v >= 0) && (v < W);
    const float* br = xr + (size_t)b * CHW + h * W;

    float xrv[C];
#pragma unroll
    for (int c = 0; c < C; ++c) xrv[c] = vin ? br[c * HW + v] : 0.0f;

    stage_row_v2(xl + (size_t)b * CHW + h * W, sXL, tid, 448);
    __syncthreads();

    bool wr = (lane >= 1) && (lane <= 62) && (v < W);   // v>=0 implied

    if (blockIdx.z == 0) {
        float sr_ = 0.f, sl_ = 0.f;
#pragma unroll
        for (int c = 0; c < C; ++c) sr_ += xrv[c] * xrv[c];
        if (vin) {
            const float4* c4 = (const float4*)(sXL + v * ESTR);
#pragma unroll
            for (int q = 0; q < 8; ++q) {
                float4 x = c4[q];
                sl_ += x.x * x.x + x.y * x.y + x.z * x.z + x.w * x.w;
            }
        }
        if (wr) {
            sqr[b * HW + h * W + v] = sr_;
            sql[b * HW + h * W + v] = sl_;
        }
    }

    float* pe = EH + (((size_t)b * D) * H + h) * W + v;
    for (int d = d0; d < d0 + DSPE; ++d) {
        int s = 2 * d;
        float e = 0.0f;
        if (vin && v + s < W) e = dot32e(xrv, sXL + (v + s) * ESTR);
        float em = __shfl_up(e, 1);
        float ep = __shfl_down(e, 1);
        float eh = em + e + ep;
        if (wr) pe[(size_t)d * HW] = eh;
    }
}

// ---------------------------------------------------------------------------
// k_lr2: sLR = vertical 3-tap of EH at column vc=w-d, times inverse norms.
#define DCH 12
__global__ __launch_bounds__(448) void k_lr2(const float* __restrict__ EH,
                                             const float* __restrict__ inl,
                                             const float* __restrict__ inr,
                                             float* __restrict__ out) {
    int w = threadIdx.x;
    int dc = blockIdx.x;              // 0..3
    int h = blockIdx.y;
    int b = blockIdx.z;
    if (w >= W) return;
    int bhw = b * HW + h * W;
    bool hm = (h > 0), hp = (h < H - 1);

    float* o = out + ((size_t)b * 3 + 2) * D * HW + h * W + w;
#pragma unroll
    for (int i = 0; i < DCH; ++i) {
        int d = dc * DCH + i;
        float r = 0.0f;
        if (w >= d && w + d < W) {
            int vc = w - d;
            const float* base = EH + ((size_t)b * D + d) * HW + vc;
            float e = base[h * W];
            if (hm) e += base[(h - 1) * W];
            if (hp) e += base[(h + 1) * W];
            float nl = inl[bhw + w + d];
            float nr = inr[bhw + vc];
            r = clip10(e * nl * nr * ISCALE);
        }
        o[(size_t)d * HW] = r;
    }
}

// ---------------------------------------------------------------------------
extern "C" void kernel_launch(void* const* d_in, const int* in_sizes, int n_in,
                              void* d_out, int out_size, void* d_ws, size_t ws_size,
                              hipStream_t stream) {
    const float* xl = (const float*)d_in[0];
    const float* xm = (const float*)d_in[1];
    const float* xr = (const float*)d_in[2];
    float* out = (float*)d_out;

    float* ws = (float*)d_ws;
    float* inl = ws;                               // B*HW
    float* inr = inl + B * HW;                     // B*HW
    float* sql = inr + B * HW;                     // B*HW
    float* sqr = sql + B * HW;                     // B*HW
    float* EH  = sqr + B * HW;                     // B*D*H*W

    k_e<<<dim3(H, B, 2), dim3(448), 0, stream>>>(xl, xr, EH, sql, sqr);
    k_norm<<<dim3((B * HW + 255) / 256), dim3(256), 0, stream>>>(sql, sqr, inl, inr);
    k_lr<<<dim3(NZ * H, B), dim3(256), 0, stream>>>(xm, xl, xr, inl, inr, out);
    k_lr2<<<dim3(4, H, B), dim3(448), 0, stream>>>(EH, inl, inr, out);
}

// Round 5
// 167.152 us; speedup vs baseline: 1.1694x; 1.1694x over previous
//
#include <hip/hip_runtime.h>
#include <math.h>

#define B 2
#define C 32
#define H 128
#define W 416
#define D 48
#define HW (H*W)
#define CHW (C*HW)
#define EPSN 1e-3f
#define ISCALE 0.05892556509887896f   // 1/sqrt(C*9)
#define ESTR 36     // k_e LDS stride (floats): stride-1 reads conflict-free
#define LSTR 32     // k_lr LDS stride: 128B columns + XOR swizzle
#define DSPL (D / 2)                   // disparities per z-block (24)

__device__ __forceinline__ float clip10(float x) {
    return fminf(fmaxf(x, -10.0f), 10.0f);
}

#define FMA4(acc, f, k, u) acc += f[4*(k)+0]*(u).x + f[4*(k)+1]*(u).y \
                               + f[4*(k)+2]*(u).z + f[4*(k)+3]*(u).w;

// ---------------------------------------------------------------------------
// k_norm: 3x3 zero-padded box of sql/sqr -> inverse patch norms inl/inr.
__global__ __launch_bounds__(256) void k_norm(const float* __restrict__ sql,
                                              const float* __restrict__ sqr,
                                              float* __restrict__ inl,
                                              float* __restrict__ inr) {
    int idx = blockIdx.x * 256 + threadIdx.x;
    if (idx >= B * HW) return;
    int b = idx / HW, hw = idx - b * HW;
    int h = hw / W, w = hw - h * W;
    float sl = 0.f, sr = 0.f;
#pragma unroll
    for (int di = -1; di <= 1; ++di) {
        int hh = h + di;
        if (hh < 0 || hh >= H) continue;
#pragma unroll
        for (int dj = -1; dj <= 1; ++dj) {
            int ww = w + dj;
            if (ww < 0 || ww >= W) continue;
            int p = b * HW + hh * W + ww;
            sl += sql[p];
            sr += sqr[p];
        }
    }
    inl[idx] = 1.0f / fmaxf(sqrtf(sl), EPSN);
    inr[idx] = 1.0f / fmaxf(sqrtf(sr), EPSN);
}

// ---------------------------------------------------------------------------
// stage_row_v2 (k_e): stage [C][W] row into LDS transposed [w][c], stride
// ESTR=36. k_e's stride-1 column reads: bank-quad (v+q)%8 covers all 8 ->
// conflict-free as-is.
__device__ __forceinline__ void stage_row_v2(const float* __restrict__ gsrc,
                                             float* __restrict__ lds,
                                             int tid, int nthreads) {
    for (int t = tid; t < (W / 4) * C; t += nthreads) {
        int rw = t & 7;
        int cl = (t >> 3) & 7;
        int g  = t >> 6;              // 0..51
        int wg = g % 13;
        int ch = g / 13;              // 0..3
        int c  = ch * 8 + cl;
        int w4 = (wg * 8 + rw) * 4;
        float4 v = *(const float4*)(gsrc + (size_t)c * HW + w4);
        lds[(w4 + 0) * ESTR + c] = v.x;
        lds[(w4 + 1) * ESTR + c] = v.y;
        lds[(w4 + 2) * ESTR + c] = v.z;
        lds[(w4 + 3) * ESTR + c] = v.w;
    }
}

// ---------------------------------------------------------------------------
// stage_row3_swz (k_lr): stage VERTICAL 3-tap vsum[c,w] (zero-pad in h) into
// 128B-stride swizzled LDS: channel-group g2 of column v -> float4 slot
// g2 ^ ((v>>1)&7). k_lr reads (v = v0+2*lane): per b128 instr, slot q^key
// covers all 8 quads x 8 lanes -> 8 dwords/bank = conflict-free minimum.
// Writes: bank = 4*(g2^k)+wd -> 32 banks, exactly 2-way = free.
__device__ __forceinline__ void stage_row3_swz(const float* __restrict__ gsrc,
                                               float* __restrict__ lds,
                                               int h, int tid, int nthreads) {
    for (int t = tid; t < (W / 4) * C; t += nthreads) {
        int rw = t & 7;
        int cl = (t >> 3) & 7;
        int g  = t >> 6;
        int wg = g % 13;
        int ch = g / 13;
        int c  = ch * 8 + cl;
        int w4 = (wg * 8 + rw) * 4;
        const float* p = gsrc + (size_t)c * HW + w4;
        float4 v = *(const float4*)(p);
        if (h > 0) {
            float4 a = *(const float4*)(p - W);
            v.x += a.x; v.y += a.y; v.z += a.z; v.w += a.w;
        }
        if (h < H - 1) {
            float4 a = *(const float4*)(p + W);
            v.x += a.x; v.y += a.y; v.z += a.z; v.w += a.w;
        }
        int g2 = c >> 2, wd = c & 3;
        int k0 = (w4 >> 1) & 7;        // key for v = w4, w4+1
        int k1 = (k0 + 1) & 7;         // key for v = w4+2, w4+3
        lds[(w4 + 0) * LSTR + 4 * (g2 ^ k0) + wd] = v.x;
        lds[(w4 + 1) * LSTR + 4 * (g2 ^ k0) + wd] = v.y;
        lds[(w4 + 2) * LSTR + 4 * (g2 ^ k1) + wd] = v.z;
        lds[(w4 + 3) * LSTR + 4 * (g2 ^ k1) + wd] = v.w;
    }
}

// ---------------------------------------------------------------------------
// dot32e (k_e): 8 b128 loads issued up front, 2 independent FMA chains.
__device__ __forceinline__ float dot32e(const float* __restrict__ x,
                                        const float* __restrict__ col) {
    const float4* c4 = (const float4*)col;
    float4 u0 = c4[0], u1 = c4[1], u2 = c4[2], u3 = c4[3];
    float4 u4 = c4[4], u5 = c4[5], u6 = c4[6], u7 = c4[7];
    float a = 0.f, b = 0.f;
    FMA4(a, x, 0, u0) FMA4(a, x, 1, u1) FMA4(a, x, 2, u2) FMA4(a, x, 3, u3)
    FMA4(b, x, 4, u4) FMA4(b, x, 5, u5) FMA4(b, x, 6, u6) FMA4(b, x, 7, u7)
    return a + b;
}

// dot2s (k_lr): swizzled column read (slot q^ky holds channels 4q..4q+3),
// two dots (w and w+1 fragments), 2 chains each.
__device__ __forceinline__ void dot2s(const float* __restrict__ fl0,
                                      const float* __restrict__ fl1,
                                      const float4* __restrict__ c4, int ky,
                                      float& a0, float& a1) {
    float4 u0 = c4[ky],     u1 = c4[1 ^ ky], u2 = c4[2 ^ ky], u3 = c4[3 ^ ky];
    float4 u4 = c4[4 ^ ky], u5 = c4[5 ^ ky], u6 = c4[6 ^ ky], u7 = c4[7 ^ ky];
    float x0 = 0.f, x1 = 0.f, y0 = 0.f, y1 = 0.f;
    FMA4(x0, fl0, 0, u0) FMA4(x0, fl0, 1, u1) FMA4(x0, fl0, 2, u2) FMA4(x0, fl0, 3, u3)
    FMA4(x1, fl0, 4, u4) FMA4(x1, fl0, 5, u5) FMA4(x1, fl0, 6, u6) FMA4(x1, fl0, 7, u7)
    FMA4(y0, fl1, 0, u0) FMA4(y0, fl1, 1, u1) FMA4(y0, fl1, 2, u2) FMA4(y0, fl1, 3, u3)
    FMA4(y1, fl1, 4, u4) FMA4(y1, fl1, 5, u5) FMA4(y1, fl1, 6, u6) FMA4(y1, fl1, 7, u7)
    a0 = x0 + x1; a1 = y0 + y1;
}

// ---------------------------------------------------------------------------
// k_lr: sL and sR — round-1 structure (grid (H,B,2), 256 thr, thread owns
// (w,w+1), rolling 3-tap over 27 column dots) with ONLY the LDS layout
// changed: LSTR 32 + XOR swizzle -> conflict-free column reads.
__global__ __launch_bounds__(256) void k_lr(const float* __restrict__ xm,
                                            const float* __restrict__ xl,
                                            const float* __restrict__ xr,
                                            const float* __restrict__ inl,
                                            const float* __restrict__ inr,
                                            float* __restrict__ out) {
    __shared__ float sB[W * LSTR];    // 53248 B
    __shared__ float sIn[W];          // 1664 B
    int tid = threadIdx.x;
    int h = blockIdx.x;
    int b = blockIdx.y;
    int d0 = blockIdx.z * DSPL;
    bool act = tid < (W / 2);         // 208 active
    int w = 2 * tid;
    int bhw = b * HW + h * W;
    const float* pm = xm + (size_t)b * CHW + h * W;

    float fl0[C], fl1[C];
    if (act) {
        float am0 = 0.f, am1 = 0.f;
#pragma unroll
        for (int c = 0; c < C; ++c) {
            float2 mv = *(const float2*)(pm + (size_t)c * HW + w);
            fl0[c] = mv.x; fl1[c] = mv.y;
            am0 += mv.x * mv.x; am1 += mv.y * mv.y;
        }
        float im0 = 1.0f / fmaxf(sqrtf(am0), EPSN);
        float im1 = 1.0f / fmaxf(sqrtf(am1), EPSN);
#pragma unroll
        for (int c = 0; c < C; ++c) { fl0[c] *= im0; fl1[c] *= im1; }
    } else {
#pragma unroll
        for (int c = 0; c < C; ++c) { fl0[c] = 0.f; fl1[c] = 0.f; }
    }

    // ---- phase L: columns v = w+d0-1+j. 3-tap completes at center m = v-1
    // at iter j>=2; store pairs (s0 from j-1, s1 from j) at j>=3, d = d0+j-3.
    stage_row3_swz(xl + (size_t)b * CHW + h * W, sB, h, tid, 256);
    for (int j = tid; j < W; j += 256) sIn[j] = inl[bhw + j];
    __syncthreads();
    if (act) {
        float* o = out + ((size_t)b * 3 + 0) * D * HW + h * W;
        float g0a = 0.f, g0b = 0.f, g1a = 0.f, g1b = 0.f, s0p = 0.f;
#pragma unroll 3
        for (int j = 0; j <= DSPL + 2; ++j) {
            int v = w + d0 - 1 + j;
            float c0 = 0.f, c1 = 0.f;
            if (v >= 0 && v < W)
                dot2s(fl0, fl1, (const float4*)(sB + v * LSTR), (v >> 1) & 7, c0, c1);
            float s0 = 0.f, s1 = 0.f;
            if (j >= 2) {
                int m = v - 1;                 // m >= 0 guaranteed
                if (m < W) {
                    float sc = sIn[m] * ISCALE;
                    s0 = clip10((g0a + g0b + c0) * sc);
                    s1 = clip10((g1a + g1b + c1) * sc);
                }
                if (j >= 3) {
                    int d = d0 + j - 3;
                    *(float2*)(o + (size_t)d * HW + w) = make_float2(s0p, s1);
                }
            }
            s0p = s0;
            g0a = g0b; g0b = c0;
            g1a = g1b; g1b = c1;
        }
    }
    __syncthreads();

    // ---- phase R: columns v = w-d0-DSPL+j ascending. Center m = v-1 at
    // iter j>=2; store pairs at j>=3 for d = d0+DSPL+2-j.
    stage_row3_swz(xr + (size_t)b * CHW + h * W, sB, h, tid, 256);
    for (int j = tid; j < W; j += 256) sIn[j] = inr[bhw + j];
    __syncthreads();
    if (act) {
        float* o = out + ((size_t)b * 3 + 1) * D * HW + h * W;
        float g0a = 0.f, g0b = 0.f, g1a = 0.f, g1b = 0.f, s0p = 0.f;
#pragma unroll 3
        for (int j = 0; j <= DSPL + 2; ++j) {
            int v = w - d0 - DSPL + j;
            float c0 = 0.f, c1 = 0.f;
            if (v >= 0 && v < W)
                dot2s(fl0, fl1, (const float4*)(sB + v * LSTR), (v >> 1) & 7, c0, c1);
            float s0 = 0.f, s1 = 0.f;
            if (j >= 2) {
                int m = v - 1;                 // m < W guaranteed
                if (m >= 0) {
                    float sc = sIn[m] * ISCALE;
                    s0 = clip10((g0a + g0b + c0) * sc);
                    s1 = clip10((g1a + g1b + c1) * sc);
                }
                if (j >= 3) {
                    int d = d0 + DSPL + 2 - j;
                    *(float2*)(o + (size_t)d * HW + w) = make_float2(s0p, s1);
                }
            }
            s0p = s0;
            g0a = g0b; g0b = c0;
            g1a = g1b; g1b = c1;
        }
    }
}

// ---------------------------------------------------------------------------
// k_e: EH[b,d,h,v] = horizontal 3-tap of E, E[v] = sum_c xl[.,v+2d]*xr[.,v].
// Round-1 structure: 448 thr, wave-halo v = wave*62+lane-1, 62 sums via
// shuffles; z splits d in two; dc==0 also emits sql/sqr. Only change: dot32e.
__global__ __launch_bounds__(448) void k_e(const float* __restrict__ xl,
                                           const float* __restrict__ xr,
                                           float* __restrict__ EH,
                                           float* __restrict__ sql,
                                           float* __restrict__ sqr) {
    __shared__ float sXL[W * ESTR];   // 59904 B
    int tid = threadIdx.x;
    int h = blockIdx.x;
    int b = blockIdx.y;
    int d0 = blockIdx.z * DSPL;
    int lane = tid & 63;
    int wv = tid >> 6;                // 0..6
    int v = wv * 62 + lane - 1;       // -1 .. 433
    bool vin = (v >= 0) && (v < W);
    const float* br = xr + (size_t)b * CHW + h * W;

    float xrv[C];
#pragma unroll
    for (int c = 0; c < C; ++c) xrv[c] = vin ? br[c * HW + v] : 0.0f;

    stage_row_v2(xl + (size_t)b * CHW + h * W, sXL, tid, 448);
    __syncthreads();

    bool wr = (lane >= 1) && (lane <= 62) && (v < W);   // v>=0 implied

    if (blockIdx.z == 0) {
        float sr_ = 0.f, sl_ = 0.f;
#pragma unroll
        for (int c = 0; c < C; ++c) sr_ += xrv[c] * xrv[c];
        if (vin) {
            const float4* c4 = (const float4*)(sXL + v * ESTR);
#pragma unroll
            for (int q = 0; q < 8; ++q) {
                float4 x = c4[q];
                sl_ += x.x * x.x + x.y * x.y + x.z * x.z + x.w * x.w;
            }
        }
        if (wr) {
            sqr[b * HW + h * W + v] = sr_;
            sql[b * HW + h * W + v] = sl_;
        }
    }

    float* pe = EH + (((size_t)b * D) * H + h) * W + v;
    for (int d = d0; d < d0 + DSPL; ++d) {
        int s = 2 * d;
        float e = 0.0f;
        if (vin && v + s < W) e = dot32e(xrv, sXL + (v + s) * ESTR);
        float em = __shfl_up(e, 1);
        float ep = __shfl_down(e, 1);
        float eh = em + e + ep;
        if (wr) pe[(size_t)d * HW] = eh;
    }
}

// ---------------------------------------------------------------------------
// k_lr2: sLR = vertical 3-tap of EH at column vc=w-d, times inverse norms.
// 1-D grid + bijective XCD swizzle (1024 = 8 x 128): each XCD owns one
// contiguous (b,dc,h)-chunk so EH row reuse (h-1,h,h+1) stays in one L2.
#define DCH 12
__global__ __launch_bounds__(448) void k_lr2(const float* __restrict__ EH,
                                             const float* __restrict__ inl,
                                             const float* __restrict__ inr,
                                             float* __restrict__ out) {
    int w = threadIdx.x;
    int lin = blockIdx.x;                       // 0..1023
    int sw = (lin & 7) * 128 + (lin >> 3);      // bijective: 1024 = 8*128
    int b  = sw >> 9;                           // /512
    int r  = sw & 511;
    int dc = r >> 7;                            // /128
    int h  = r & 127;
    if (w >= W) return;
    int bhw = b * HW + h * W;
    bool hm = (h > 0), hp = (h < H - 1);

    float* o = out + ((size_t)b * 3 + 2) * D * HW + h * W + w;
#pragma unroll
    for (int i = 0; i < DCH; ++i) {
        int d = dc * DCH + i;
        float r2 = 0.0f;
        if (w >= d && w + d < W) {
            int vc = w - d;
            const float* base = EH + ((size_t)b * D + d) * HW + vc;
            float e = base[h * W];
            if (hm) e += base[(h - 1) * W];
            if (hp) e += base[(h + 1) * W];
            float nl = inl[bhw + w + d];
            float nr = inr[bhw + vc];
            r2 = clip10(e * nl * nr * ISCALE);
        }
        o[(size_t)d * HW] = r2;
    }
}

// ---------------------------------------------------------------------------
extern "C" void kernel_launch(void* const* d_in, const int* in_sizes, int n_in,
                              void* d_out, int out_size, void* d_ws, size_t ws_size,
                              hipStream_t stream) {
    const float* xl = (const float*)d_in[0];
    const float* xm = (const float*)d_in[1];
    const float* xr = (const float*)d_in[2];
    float* out = (float*)d_out;

    float* ws = (float*)d_ws;
    float* inl = ws;                               // B*HW
    float* inr = inl + B * HW;                     // B*HW
    float* sql = inr + B * HW;                     // B*HW
    float* sqr = sql + B * HW;                     // B*HW
    float* EH  = sqr + B * HW;                     // B*D*H*W

    k_e<<<dim3(H, B, 2), dim3(448), 0, stream>>>(xl, xr, EH, sql, sqr);
    k_norm<<<dim3((B * HW + 255) / 256), dim3(256), 0, stream>>>(sql, sqr, inl, inr);
    k_lr<<<dim3(H, B, 2), dim3(256), 0, stream>>>(xm, xl, xr, inl, inr, out);
    k_lr2<<<dim3(4 * H * B), dim3(448), 0, stream>>>(EH, inl, inr, out);
}

// Round 7
// 164.738 us; speedup vs baseline: 1.1866x; 1.0147x over previous
//
#include <hip/hip_runtime.h>
#include <math.h>

#define B 2
#define C 32
#define H 128
#define W 416
#define D 48
#define HW (H*W)
#define CHW (C*HW)
#define EPSN 1e-3f
#define ISCALE 0.05892556509887896f   // 1/sqrt(C*9)
#define ESTR 36     // k_e LDS stride (floats): stride-1 reads conflict-free
#define LSTR 32     // k_lr LDS stride: 128B columns + XOR swizzle
#define DSPL (D / 2)                   // disparities per z-block (24)

__device__ __forceinline__ float clip10(float x) {
    return fminf(fmaxf(x, -10.0f), 10.0f);
}

#define FMA4(acc, f, k, u) acc += f[4*(k)+0]*(u).x + f[4*(k)+1]*(u).y \
                               + f[4*(k)+2]*(u).z + f[4*(k)+3]*(u).w;

#define CLW(v) ((v) < 0 ? 0 : ((v) > (W - 1) ? (W - 1) : (v)))

// ---------------------------------------------------------------------------
// k_norm: 3x3 zero-padded box of sql/sqr -> inverse patch norms inl/inr.
__global__ __launch_bounds__(256) void k_norm(const float* __restrict__ sql,
                                              const float* __restrict__ sqr,
                                              float* __restrict__ inl,
                                              float* __restrict__ inr) {
    int idx = blockIdx.x * 256 + threadIdx.x;
    if (idx >= B * HW) return;
    int b = idx / HW, hw = idx - b * HW;
    int h = hw / W, w = hw - h * W;
    float sl = 0.f, sr = 0.f;
#pragma unroll
    for (int di = -1; di <= 1; ++di) {
        int hh = h + di;
        if (hh < 0 || hh >= H) continue;
#pragma unroll
        for (int dj = -1; dj <= 1; ++dj) {
            int ww = w + dj;
            if (ww < 0 || ww >= W) continue;
            int p = b * HW + hh * W + ww;
            sl += sql[p];
            sr += sqr[p];
        }
    }
    inl[idx] = 1.0f / fmaxf(sqrtf(sl), EPSN);
    inr[idx] = 1.0f / fmaxf(sqrtf(sr), EPSN);
}

// ---------------------------------------------------------------------------
// stage_row_v2 (k_e): stage [C][W] row into LDS transposed [w][c], stride
// ESTR=36. k_e's stride-1 column reads: bank stride 36≡4 mod 32 -> 8 lanes
// per bank-quad, all 32 banks covered = structural minimum.
__device__ __forceinline__ void stage_row_v2(const float* __restrict__ gsrc,
                                             float* __restrict__ lds,
                                             int tid, int nthreads) {
    for (int t = tid; t < (W / 4) * C; t += nthreads) {
        int rw = t & 7;
        int cl = (t >> 3) & 7;
        int g  = t >> 6;              // 0..51
        int wg = g % 13;
        int ch = g / 13;              // 0..3
        int c  = ch * 8 + cl;
        int w4 = (wg * 8 + rw) * 4;
        float4 v = *(const float4*)(gsrc + (size_t)c * HW + w4);
        lds[(w4 + 0) * ESTR + c] = v.x;
        lds[(w4 + 1) * ESTR + c] = v.y;
        lds[(w4 + 2) * ESTR + c] = v.z;
        lds[(w4 + 3) * ESTR + c] = v.w;
    }
}

// ---------------------------------------------------------------------------
// stage_row3_swz (k_lr): stage VERTICAL 3-tap vsum[c,w] (zero-pad in h) into
// 128B-stride swizzled LDS: channel-group g2 of column v -> float4 slot
// g2 ^ ((v>>1)&7). Reads (v = v0+2*lane): slot q^key spans all 8 quads x
// 8 lanes -> 8 dwords/bank = conflict-free minimum. Writes: bank =
// 4*(g2^k)+wd -> 32 banks, exactly 2-way = free.
__device__ __forceinline__ void stage_row3_swz(const float* __restrict__ gsrc,
                                               float* __restrict__ lds,
                                               int h, int tid, int nthreads) {
    for (int t = tid; t < (W / 4) * C; t += nthreads) {
        int rw = t & 7;
        int cl = (t >> 3) & 7;
        int g  = t >> 6;
        int wg = g % 13;
        int ch = g / 13;
        int c  = ch * 8 + cl;
        int w4 = (wg * 8 + rw) * 4;
        const float* p = gsrc + (size_t)c * HW + w4;
        float4 v = *(const float4*)(p);
        if (h > 0) {
            float4 a = *(const float4*)(p - W);
            v.x += a.x; v.y += a.y; v.z += a.z; v.w += a.w;
        }
        if (h < H - 1) {
            float4 a = *(const float4*)(p + W);
            v.x += a.x; v.y += a.y; v.z += a.z; v.w += a.w;
        }
        int g2 = c >> 2, wd = c & 3;
        int k0 = (w4 >> 1) & 7;        // key for v = w4, w4+1
        int k1 = (k0 + 1) & 7;         // key for v = w4+2, w4+3
        lds[(w4 + 0) * LSTR + 4 * (g2 ^ k0) + wd] = v.x;
        lds[(w4 + 1) * LSTR + 4 * (g2 ^ k0) + wd] = v.y;
        lds[(w4 + 2) * LSTR + 4 * (g2 ^ k1) + wd] = v.z;
        lds[(w4 + 3) * LSTR + 4 * (g2 ^ k1) + wd] = v.w;
    }
}

// ---------------------------------------------------------------------------
// k_lr: sL and sR — r1 structure (grid (H,B,2), 256 thr, thread owns
// (w,w+1), rolling 3-tap over 27 column dots) + swizzled LDS + REGISTER
// DOUBLE-BUFFER: column j+1's 8 ds_read_b128 are issued before column j's
// FMAs so LDS latency hides under compute (named RA/RB buffers, static idx).
__global__ __launch_bounds__(256) void k_lr(const float* __restrict__ xm,
                                            const float* __restrict__ xl,
                                            const float* __restrict__ xr,
                                            const float* __restrict__ inl,
                                            const float* __restrict__ inr,
                                            float* __restrict__ out) {
    __shared__ float sB[W * LSTR];    // 53248 B
    __shared__ float sIn[W];          // 1664 B
    int tid = threadIdx.x;
    int h = blockIdx.x;
    int b = blockIdx.y;
    int d0 = blockIdx.z * DSPL;
    bool act = tid < (W / 2);         // 208 active
    int w = 2 * tid;
    int bhw = b * HW + h * W;
    const float* pm = xm + (size_t)b * CHW + h * W;

    float fl0[C], fl1[C];
    if (act) {
        float am0 = 0.f, am1 = 0.f;
#pragma unroll
        for (int c = 0; c < C; ++c) {
            float2 mv = *(const float2*)(pm + (size_t)c * HW + w);
            fl0[c] = mv.x; fl1[c] = mv.y;
            am0 += mv.x * mv.x; am1 += mv.y * mv.y;
        }
        float im0 = 1.0f / fmaxf(sqrtf(am0), EPSN);
        float im1 = 1.0f / fmaxf(sqrtf(am1), EPSN);
#pragma unroll
        for (int c = 0; c < C; ++c) { fl0[c] *= im0; fl1[c] *= im1; }
    } else {
#pragma unroll
        for (int c = 0; c < C; ++c) { fl0[c] = 0.f; fl1[c] = 0.f; }
    }

    float4 RA0, RA1, RA2, RA3, RA4, RA5, RA6, RA7;
    float4 RB0, RB1, RB2, RB3, RB4, RB5, RB6, RB7;

#define LOADU(P, vv) { int _vq = CLW(vv); \
    const float4* _c4 = (const float4*)(sB + (size_t)_vq * LSTR); \
    int _ky = (_vq >> 1) & 7; \
    P##0 = _c4[_ky];     P##1 = _c4[1 ^ _ky]; P##2 = _c4[2 ^ _ky]; P##3 = _c4[3 ^ _ky]; \
    P##4 = _c4[4 ^ _ky]; P##5 = _c4[5 ^ _ky]; P##6 = _c4[6 ^ _ky]; P##7 = _c4[7 ^ _ky]; }

#define DOT2U(P, c0, c1) { float _x0=0.f,_x1=0.f,_y0=0.f,_y1=0.f; \
    FMA4(_x0, fl0, 0, P##0) FMA4(_x0, fl0, 1, P##1) FMA4(_x0, fl0, 2, P##2) FMA4(_x0, fl0, 3, P##3) \
    FMA4(_x1, fl0, 4, P##4) FMA4(_x1, fl0, 5, P##5) FMA4(_x1, fl0, 6, P##6) FMA4(_x1, fl0, 7, P##7) \
    FMA4(_y0, fl1, 0, P##0) FMA4(_y0, fl1, 1, P##1) FMA4(_y0, fl1, 2, P##2) FMA4(_y0, fl1, 3, P##3) \
    FMA4(_y1, fl1, 4, P##4) FMA4(_y1, fl1, 5, P##5) FMA4(_y1, fl1, 6, P##6) FMA4(_y1, fl1, 7, P##7) \
    c0 = _x0 + _x1; c1 = _y0 + _y1; }

    // ---- phase L: columns v = w+d0-1+j, j=0..26. Center m=v-1 done at
    // j>=2; store pairs (s0 from j-1, s1 from j) at j>=3, d = d0+j-3.
    stage_row3_swz(xl + (size_t)b * CHW + h * W, sB, h, tid, 256);
    for (int j = tid; j < W; j += 256) sIn[j] = inl[bhw + j];
    __syncthreads();
    if (act) {
        float* oL = out + ((size_t)b * 3 + 0) * D * HW + h * W;
        const int vb = w + d0 - 1;
        float g0a = 0.f, g0b = 0.f, g1a = 0.f, g1b = 0.f, s0p = 0.f;
#define STEPL(P, jj) { int v = vb + (jj); bool ok = (v >= 0) && (v < W); \
    float c0, c1; DOT2U(P, c0, c1); c0 = ok ? c0 : 0.f; c1 = ok ? c1 : 0.f; \
    float s0 = 0.f, s1 = 0.f; \
    if ((jj) >= 2) { int m = v - 1; \
        if (m < W) { float sc = sIn[m] * ISCALE; \
            s0 = clip10((g0a + g0b + c0) * sc); s1 = clip10((g1a + g1b + c1) * sc); } \
        if ((jj) >= 3) { int d = d0 + (jj) - 3; \
            *(float2*)(oL + (size_t)d * HW + w) = make_float2(s0p, s1); } } \
    s0p = s0; g0a = g0b; g0b = c0; g1a = g1b; g1b = c1; }
        LOADU(RA, vb);
#pragma unroll 2
        for (int j = 0; j < DSPL + 2; j += 2) {   // steps 0..25; tail 26
            LOADU(RB, vb + j + 1);
            STEPL(RA, j);
            LOADU(RA, vb + j + 2);
            STEPL(RB, j + 1);
        }
        STEPL(RA, DSPL + 2);
#undef STEPL
    }
    __syncthreads();

    // ---- phase R: columns v = w-d0-DSPL+j, j=0..26, ascending. Center
    // m=v-1 at j>=2; store pairs at j>=3 for d = d0+DSPL+2-j.
    stage_row3_swz(xr + (size_t)b * CHW + h * W, sB, h, tid, 256);
    for (int j = tid; j < W; j += 256) sIn[j] = inr[bhw + j];
    __syncthreads();
    if (act) {
        float* oR = out + ((size_t)b * 3 + 1) * D * HW + h * W;
        const int vb = w - d0 - DSPL;
        float g0a = 0.f, g0b = 0.f, g1a = 0.f, g1b = 0.f, s0p = 0.f;
#define STEPR(P, jj) { int v = vb + (jj); bool ok = (v >= 0) && (v < W); \
    float c0, c1; DOT2U(P, c0, c1); c0 = ok ? c0 : 0.f; c1 = ok ? c1 : 0.f; \
    float s0 = 0.f, s1 = 0.f; \
    if ((jj) >= 2) { int m = v - 1; \
        if (m >= 0) { float sc = sIn[m] * ISCALE; \
            s0 = clip10((g0a + g0b + c0) * sc); s1 = clip10((g1a + g1b + c1) * sc); } \
        if ((jj) >= 3) { int d = d0 + DSPL + 2 - (jj); \
            *(float2*)(oR + (size_t)d * HW + w) = make_float2(s0p, s1); } } \
    s0p = s0; g0a = g0b; g0b = c0; g1a = g1b; g1b = c1; }
        LOADU(RA, vb);
#pragma unroll 2
        for (int j = 0; j < DSPL + 2; j += 2) {
            LOADU(RB, vb + j + 1);
            STEPR(RA, j);
            LOADU(RA, vb + j + 2);
            STEPR(RB, j + 1);
        }
        STEPR(RA, DSPL + 2);
#undef STEPR
    }
#undef LOADU
#undef DOT2U
}

// ---------------------------------------------------------------------------
// k_e: EH[b,d,h,v] = horizontal 3-tap of E, E[v] = sum_c xl[.,v+2d]*xr[.,v].
// r1 structure (448 thr, wave-halo v = wave*62+lane-1, shuffled 3-tap,
// z splits d in two, dc==0 emits sql/sqr) + REGISTER DOUBLE-BUFFER on the
// d-loop: column for d+1 loads while d's FMAs run. launch_bounds(448,4)
// caps VGPR at 128 so 2 blocks (14 waves) stay resident.
__global__ __launch_bounds__(448, 4) void k_e(const float* __restrict__ xl,
                                              const float* __restrict__ xr,
                                              float* __restrict__ EH,
                                              float* __restrict__ sql,
                                              float* __restrict__ sqr) {
    __shared__ float sXL[W * ESTR];   // 59904 B
    int tid = threadIdx.x;
    int h = blockIdx.x;
    int b = blockIdx.y;
    int d0 = blockIdx.z * DSPL;
    int lane = tid & 63;
    int wv = tid >> 6;                // 0..6
    int v = wv * 62 + lane - 1;       // -1 .. 433
    bool vin = (v >= 0) && (v < W);
    const float* br = xr + (size_t)b * CHW + h * W;

    float xrv[C];
#pragma unroll
    for (int c = 0; c < C; ++c) xrv[c] = vin ? br[c * HW + v] : 0.0f;

    stage_row_v2(xl + (size_t)b * CHW + h * W, sXL, tid, 448);
    __syncthreads();

    bool wr = (lane >= 1) && (lane <= 62) && (v < W);   // v>=0 implied

    if (blockIdx.z == 0) {
        float sr_ = 0.f, sl_ = 0.f;
#pragma unroll
        for (int c = 0; c < C; ++c) sr_ += xrv[c] * xrv[c];
        if (vin) {
            const float4* c4 = (const float4*)(sXL + v * ESTR);
#pragma unroll
            for (int q = 0; q < 8; ++q) {
                float4 x = c4[q];
                sl_ += x.x * x.x + x.y * x.y + x.z * x.z + x.w * x.w;
            }
        }
        if (wr) {
            sqr[b * HW + h * W + v] = sr_;
            sql[b * HW + h * W + v] = sl_;
        }
    }

    float* pe = EH + (((size_t)b * D) * H + h) * W + v;

    float4 RA0, RA1, RA2, RA3, RA4, RA5, RA6, RA7;
    float4 RB0, RB1, RB2, RB3, RB4, RB5, RB6, RB7;

#define LOADE(P, col) { int _vq = CLW(col); \
    const float4* _c4 = (const float4*)(sXL + (size_t)_vq * ESTR); \
    P##0 = _c4[0]; P##1 = _c4[1]; P##2 = _c4[2]; P##3 = _c4[3]; \
    P##4 = _c4[4]; P##5 = _c4[5]; P##6 = _c4[6]; P##7 = _c4[7]; }
#define STEPE(P, dd) { float _a = 0.f, _b = 0.f; \
    FMA4(_a, xrv, 0, P##0) FMA4(_a, xrv, 1, P##1) FMA4(_a, xrv, 2, P##2) FMA4(_a, xrv, 3, P##3) \
    FMA4(_b, xrv, 4, P##4) FMA4(_b, xrv, 5, P##5) FMA4(_b, xrv, 6, P##6) FMA4(_b, xrv, 7, P##7) \
    float e = (vin && (v + 2 * (dd)) < W) ? (_a + _b) : 0.f; \
    float em = __shfl_up(e, 1); \
    float ep = __shfl_down(e, 1); \
    float eh = em + e + ep; \
    if (wr) pe[(size_t)(dd) * HW] = eh; }

    LOADE(RA, v + 2 * d0);
#pragma unroll 2
    for (int d = d0; d < d0 + DSPL; d += 2) {
        LOADE(RB, v + 2 * d + 2);
        STEPE(RA, d);
        LOADE(RA, v + 2 * d + 4);
        STEPE(RB, d + 1);
    }
#undef LOADE
#undef STEPE
}

// ---------------------------------------------------------------------------
// k_lr2: sLR = vertical 3-tap of EH at column vc=w-d, times inverse norms.
// (r1-measured-good form: grid (4,H,B).)
#define DCH 12
__global__ __launch_bounds__(448) void k_lr2(const float* __restrict__ EH,
                                             const float* __restrict__ inl,
                                             const float* __restrict__ inr,
                                             float* __restrict__ out) {
    int w = threadIdx.x;
    int dc = blockIdx.x;              // 0..3
    int h = blockIdx.y;
    int b = blockIdx.z;
    if (w >= W) return;
    int bhw = b * HW + h * W;
    bool hm = (h > 0), hp = (h < H - 1);

    float* o = out + ((size_t)b * 3 + 2) * D * HW + h * W + w;
#pragma unroll
    for (int i = 0; i < DCH; ++i) {
        int d = dc * DCH + i;
        float r = 0.0f;
        if (w >= d && w + d < W) {
            int vc = w - d;
            const float* base = EH + ((size_t)b * D + d) * HW + vc;
            float e = base[h * W];
            if (hm) e += base[(h - 1) * W];
            if (hp) e += base[(h + 1) * W];
            float nl = inl[bhw + w + d];
            float nr = inr[bhw + vc];
            r = clip10(e * nl * nr * ISCALE);
        }
        o[(size_t)d * HW] = r;
    }
}

// ---------------------------------------------------------------------------
extern "C" void kernel_launch(void* const* d_in, const int* in_sizes, int n_in,
                              void* d_out, int out_size, void* d_ws, size_t ws_size,
                              hipStream_t stream) {
    const float* xl = (const float*)d_in[0];
    const float* xm = (const float*)d_in[1];
    const float* xr = (const float*)d_in[2];
    float* out = (float*)d_out;

    float* ws = (float*)d_ws;
    float* inl = ws;                               // B*HW
    float* inr = inl + B * HW;                     // B*HW
    float* sql = inr + B * HW;                     // B*HW
    float* sqr = sql + B * HW;                     // B*HW
    float* EH  = sqr + B * HW;                     // B*D*H*W

    k_e<<<dim3(H, B, 2), dim3(448), 0, stream>>>(xl, xr, EH, sql, sqr);
    k_norm<<<dim3((B * HW + 255) / 256), dim3(256), 0, stream>>>(sql, sqr, inl, inr);
    k_lr<<<dim3(H, B, 2), dim3(256), 0, stream>>>(xm, xl, xr, inl, inr, out);
    k_lr2<<<dim3(4, H, B), dim3(448), 0, stream>>>(EH, inl, inr, out);
}

// Round 11
// 164.328 us; speedup vs baseline: 1.1895x; 1.0025x over previous
//
#include <hip/hip_runtime.h>
#include <math.h>

#define B 2
#define C 32
#define H 128
#define W 416
#define D 48
#define HW (H*W)
#define CHW (C*HW)
#define EPSN 1e-3f
#define ISCALE 0.05892556509887896f   // 1/sqrt(C*9)
#define ESTR 36     // k_e LDS stride (floats): stride-1 reads conflict-free
#define DSPL (D / 2)                   // disparities per z-block (24)

typedef _Float16 h16;
typedef _Float16 __attribute__((ext_vector_type(2))) h16x2;

__device__ __forceinline__ float clip10(float x) {
    return fminf(fmaxf(x, -10.0f), 10.0f);
}

__device__ __forceinline__ float fdot2(h16x2 a, h16x2 bb, float c) {
    return __builtin_amdgcn_fdot2(a, bb, c, false);
}
__device__ __forceinline__ h16x2 u2h(unsigned int u) {
    union { unsigned int u; h16x2 h; } cv; cv.u = u; return cv.h;
}
__device__ __forceinline__ unsigned int pkh(float a, float bb) {
    union { h16x2 h; unsigned int u; } cv;
    cv.h = h16x2{(h16)a, (h16)bb}; return cv.u;
}

#define FMA4(acc, f, k, u) acc += f[4*(k)+0]*(u).x + f[4*(k)+1]*(u).y \
                               + f[4*(k)+2]*(u).z + f[4*(k)+3]*(u).w;

#define CLW(v) ((v) < 0 ? 0 : ((v) > (W - 1) ? (W - 1) : (v)))

// ---------------------------------------------------------------------------
// k_norm: 3x3 zero-padded box of sql/sqr -> inverse patch norms inl/inr.
__global__ __launch_bounds__(256) void k_norm(const float* __restrict__ sql,
                                              const float* __restrict__ sqr,
                                              float* __restrict__ inl,
                                              float* __restrict__ inr) {
    int idx = blockIdx.x * 256 + threadIdx.x;
    if (idx >= B * HW) return;
    int b = idx / HW, hw = idx - b * HW;
    int h = hw / W, w = hw - h * W;
    float sl = 0.f, sr = 0.f;
#pragma unroll
    for (int di = -1; di <= 1; ++di) {
        int hh = h + di;
        if (hh < 0 || hh >= H) continue;
#pragma unroll
        for (int dj = -1; dj <= 1; ++dj) {
            int ww = w + dj;
            if (ww < 0 || ww >= W) continue;
            int p = b * HW + hh * W + ww;
            sl += sql[p];
            sr += sqr[p];
        }
    }
    inl[idx] = 1.0f / fmaxf(sqrtf(sl), EPSN);
    inr[idx] = 1.0f / fmaxf(sqrtf(sr), EPSN);
}

// ---------------------------------------------------------------------------
// stage_row_v2 (k_e): stage [C][W] row into LDS transposed [w][c], stride
// ESTR=36 (fp32, unchanged r7-good).
__device__ __forceinline__ void stage_row_v2(const float* __restrict__ gsrc,
                                             float* __restrict__ lds,
                                             int tid, int nthreads) {
    for (int t = tid; t < (W / 4) * C; t += nthreads) {
        int rw = t & 7;
        int cl = (t >> 3) & 7;
        int g  = t >> 6;              // 0..51
        int wg = g % 13;
        int ch = g / 13;              // 0..3
        int c  = ch * 8 + cl;
        int w4 = (wg * 8 + rw) * 4;
        float4 v = *(const float4*)(gsrc + (size_t)c * HW + w4);
        lds[(w4 + 0) * ESTR + c] = v.x;
        lds[(w4 + 1) * ESTR + c] = v.y;
        lds[(w4 + 2) * ESTR + c] = v.z;
        lds[(w4 + 3) * ESTR + c] = v.w;
    }
}

// ---------------------------------------------------------------------------
// stage_row3_h (k_lr): stage VERTICAL 3-tap vsum as PACKED fp16 channel-pairs.
// Column v = 16 dwords (dword dw = channels 2dw,2dw+1), 64 B. Layout:
//   base dword  = 16 * (v ^ ((v>>1)&1))      (swaps 64B halves of 128B pairs
//                                             so stride-2 readers span bank bit 4)
//   phys dword  = 4*((dw>>2) ^ ky(v)) + (dw&3),  ky(v) = ((v>>1)^(v>>2))&3
// Read check (v = v0+2*lane): (bank-bit4, ky) take 8 distinct combos per 8
// lanes -> all 32 banks, 8 dwords/bank = structural min, conflict-free.
// Write check: 4-way (1.58x) on half the instructions ~ net free.
__device__ __forceinline__ void stage_row3_h(const float* __restrict__ gsrc,
                                             unsigned int* __restrict__ lds,
                                             int h, int tid, int nthreads) {
    for (int t = tid; t < (W / 4) * (C / 2); t += nthreads) {   // 1664 items
        int p = t & 15;               // channel pair 0..15
        int u = t >> 4;               // column quad 0..103
        int v0 = 4 * u;
        const float* pa = gsrc + (size_t)(2 * p) * HW + v0;
        const float* pb = pa + HW;
        float4 va = *(const float4*)pa;
        float4 vb = *(const float4*)pb;
        if (h > 0) {
            float4 xa = *(const float4*)(pa - W);
            float4 xb = *(const float4*)(pb - W);
            va.x += xa.x; va.y += xa.y; va.z += xa.z; va.w += xa.w;
            vb.x += xb.x; vb.y += xb.y; vb.z += xb.z; vb.w += xb.w;
        }
        if (h < H - 1) {
            float4 xa = *(const float4*)(pa + W);
            float4 xb = *(const float4*)(pb + W);
            va.x += xa.x; va.y += xa.y; va.z += xa.z; va.w += xa.w;
            vb.x += xb.x; vb.y += xb.y; vb.z += xb.z; vb.w += xb.w;
        }
        int q = p >> 2, lo = p & 3;
        unsigned int pk0 = pkh(va.x, vb.x);
        unsigned int pk1 = pkh(va.y, vb.y);
        unsigned int pk2 = pkh(va.z, vb.z);
        unsigned int pk3 = pkh(va.w, vb.w);
#define PUTH(vv, val) { int _v = (vv); \
    lds[16 * (_v ^ ((_v >> 1) & 1)) \
        + 4 * (q ^ ((((_v) >> 1) ^ ((_v) >> 2)) & 3)) + lo] = (val); }
        PUTH(v0 + 0, pk0)
        PUTH(v0 + 1, pk1)
        PUTH(v0 + 2, pk2)
        PUTH(v0 + 3, pk3)
#undef PUTH
    }
}

// ---------------------------------------------------------------------------
// dot32e (k_e): 8 b128 loads issued up front, 2 independent FMA chains.
__device__ __forceinline__ float dot32e(const float* __restrict__ x,
                                        const float* __restrict__ col) {
    const float4* c4 = (const float4*)col;
    float4 u0 = c4[0], u1 = c4[1], u2 = c4[2], u3 = c4[3];
    float4 u4 = c4[4], u5 = c4[5], u6 = c4[6], u7 = c4[7];
    float a = 0.f, bb = 0.f;
    FMA4(a, x, 0, u0) FMA4(a, x, 1, u1) FMA4(a, x, 2, u2) FMA4(a, x, 3, u3)
    FMA4(bb, x, 4, u4) FMA4(bb, x, 5, u5) FMA4(bb, x, 6, u6) FMA4(bb, x, 7, u7)
    return a + bb;
}

// ---------------------------------------------------------------------------
// k_lr: sL and sR — r7 structure (grid (H,B,2), 256 thr, thread owns
// (w,w+1), rolling 3-tap over 27 column dots, register double-buffer) with
// the LDS tile in PACKED fp16 (4 b128/column, half the LDS-pipe time) and
// dots via v_dot2_f32_f16 (32 dot2 + 2 adds vs ~70 fp32 VALU).
__global__ __launch_bounds__(256) void k_lr(const float* __restrict__ xm,
                                            const float* __restrict__ xl,
                                            const float* __restrict__ xr,
                                            const float* __restrict__ inl,
                                            const float* __restrict__ inr,
                                            float* __restrict__ out) {
    __shared__ unsigned int sBu[W * 16];   // 26624 B
    __shared__ float sIn[W];               // 1664 B
    int tid = threadIdx.x;
    int h = blockIdx.x;
    int b = blockIdx.y;
    int d0 = blockIdx.z * DSPL;
    bool act = tid < (W / 2);         // 208 active
    int w = 2 * tid;
    int bhw = b * HW + h * W;
    const float* pm = xm + (size_t)b * CHW + h * W;

    // fl for w and w+1, normalized, packed to fp16 channel-pairs.
    h16x2 f0h[16], f1h[16];
    if (act) {
        float t0[C], t1[C];
        float am0 = 0.f, am1 = 0.f;
#pragma unroll
        for (int c = 0; c < C; ++c) {
            float2 mv = *(const float2*)(pm + (size_t)c * HW + w);
            t0[c] = mv.x; t1[c] = mv.y;
            am0 += mv.x * mv.x; am1 += mv.y * mv.y;
        }
        float im0 = 1.0f / fmaxf(sqrtf(am0), EPSN);
        float im1 = 1.0f / fmaxf(sqrtf(am1), EPSN);
#pragma unroll
        for (int j = 0; j < 16; ++j) {
            f0h[j] = h16x2{(h16)(t0[2 * j] * im0), (h16)(t0[2 * j + 1] * im0)};
            f1h[j] = h16x2{(h16)(t1[2 * j] * im1), (h16)(t1[2 * j + 1] * im1)};
        }
    } else {
#pragma unroll
        for (int j = 0; j < 16; ++j) { f0h[j] = h16x2{(h16)0.f, (h16)0.f};
                                       f1h[j] = h16x2{(h16)0.f, (h16)0.f}; }
    }

    uint4 RA0, RA1, RA2, RA3;
    uint4 RB0, RB1, RB2, RB3;

#define LOADH(P, vv) { int _v = CLW(vv); \
    const uint4* _c4 = (const uint4*)(sBu + 16 * (_v ^ ((_v >> 1) & 1))); \
    int _ky = ((_v >> 1) ^ (_v >> 2)) & 3; \
    P##0 = _c4[_ky]; P##1 = _c4[1 ^ _ky]; P##2 = _c4[2 ^ _ky]; P##3 = _c4[3 ^ _ky]; }

#define DOTH(P, c0, c1) { \
    float _a0 = 0.f, _a1 = 0.f, _b0 = 0.f, _b1 = 0.f; \
    _a0 = fdot2(f0h[0],  u2h((P##0).x), _a0); _a0 = fdot2(f0h[1],  u2h((P##0).y), _a0); \
    _a0 = fdot2(f0h[2],  u2h((P##0).z), _a0); _a0 = fdot2(f0h[3],  u2h((P##0).w), _a0); \
    _a0 = fdot2(f0h[4],  u2h((P##1).x), _a0); _a0 = fdot2(f0h[5],  u2h((P##1).y), _a0); \
    _a0 = fdot2(f0h[6],  u2h((P##1).z), _a0); _a0 = fdot2(f0h[7],  u2h((P##1).w), _a0); \
    _a1 = fdot2(f0h[8],  u2h((P##2).x), _a1); _a1 = fdot2(f0h[9],  u2h((P##2).y), _a1); \
    _a1 = fdot2(f0h[10], u2h((P##2).z), _a1); _a1 = fdot2(f0h[11], u2h((P##2).w), _a1); \
    _a1 = fdot2(f0h[12], u2h((P##3).x), _a1); _a1 = fdot2(f0h[13], u2h((P##3).y), _a1); \
    _a1 = fdot2(f0h[14], u2h((P##3).z), _a1); _a1 = fdot2(f0h[15], u2h((P##3).w), _a1); \
    _b0 = fdot2(f1h[0],  u2h((P##0).x), _b0); _b0 = fdot2(f1h[1],  u2h((P##0).y), _b0); \
    _b0 = fdot2(f1h[2],  u2h((P##0).z), _b0); _b0 = fdot2(f1h[3],  u2h((P##0).w), _b0); \
    _b0 = fdot2(f1h[4],  u2h((P##1).x), _b0); _b0 = fdot2(f1h[5],  u2h((P##1).y), _b0); \
    _b0 = fdot2(f1h[6],  u2h((P##1).z), _b0); _b0 = fdot2(f1h[7],  u2h((P##1).w), _b0); \
    _b1 = fdot2(f1h[8],  u2h((P##2).x), _b1); _b1 = fdot2(f1h[9],  u2h((P##2).y), _b1); \
    _b1 = fdot2(f1h[10], u2h((P##2).z), _b1); _b1 = fdot2(f1h[11], u2h((P##2).w), _b1); \
    _b1 = fdot2(f1h[12], u2h((P##3).x), _b1); _b1 = fdot2(f1h[13], u2h((P##3).y), _b1); \
    _b1 = fdot2(f1h[14], u2h((P##3).z), _b1); _b1 = fdot2(f1h[15], u2h((P##3).w), _b1); \
    c0 = _a0 + _a1; c1 = _b0 + _b1; }

    // ---- phase L: columns v = w+d0-1+j, j=0..26. Center m=v-1 done at
    // j>=2; store pairs (s0 from j-1, s1 from j) at j>=3, d = d0+j-3.
    stage_row3_h(xl + (size_t)b * CHW + h * W, sBu, h, tid, 256);
    for (int j = tid; j < W; j += 256) sIn[j] = inl[bhw + j];
    __syncthreads();
    if (act) {
        float* oL = out + ((size_t)b * 3 + 0) * D * HW + h * W;
        const int vb = w + d0 - 1;
        float g0a = 0.f, g0b = 0.f, g1a = 0.f, g1b = 0.f, s0p = 0.f;
#define STEPL(P, jj) { int v = vb + (jj); bool ok = (v >= 0) && (v < W); \
    float c0, c1; DOTH(P, c0, c1); c0 = ok ? c0 : 0.f; c1 = ok ? c1 : 0.f; \
    float s0 = 0.f, s1 = 0.f; \
    if ((jj) >= 2) { int m = v - 1; \
        if (m < W) { float sc = sIn[m] * ISCALE; \
            s0 = clip10((g0a + g0b + c0) * sc); s1 = clip10((g1a + g1b + c1) * sc); } \
        if ((jj) >= 3) { int d = d0 + (jj) - 3; \
            *(float2*)(oL + (size_t)d * HW + w) = make_float2(s0p, s1); } } \
    s0p = s0; g0a = g0b; g0b = c0; g1a = g1b; g1b = c1; }
        LOADH(RA, vb);
#pragma unroll 2
        for (int j = 0; j < DSPL + 2; j += 2) {   // steps 0..25; tail 26
            LOADH(RB, vb + j + 1);
            STEPL(RA, j);
            LOADH(RA, vb + j + 2);
            STEPL(RB, j + 1);
        }
        STEPL(RA, DSPL + 2);
#undef STEPL
    }
    __syncthreads();

    // ---- phase R: columns v = w-d0-DSPL+j, j=0..26, ascending. Center
    // m=v-1 at j>=2; store pairs at j>=3 for d = d0+DSPL+2-j.
    stage_row3_h(xr + (size_t)b * CHW + h * W, sBu, h, tid, 256);
    for (int j = tid; j < W; j += 256) sIn[j] = inr[bhw + j];
    __syncthreads();
    if (act) {
        float* oR = out + ((size_t)b * 3 + 1) * D * HW + h * W;
        const int vb = w - d0 - DSPL;
        float g0a = 0.f, g0b = 0.f, g1a = 0.f, g1b = 0.f, s0p = 0.f;
#define STEPR(P, jj) { int v = vb + (jj); bool ok = (v >= 0) && (v < W); \
    float c0, c1; DOTH(P, c0, c1); c0 = ok ? c0 : 0.f; c1 = ok ? c1 : 0.f; \
    float s0 = 0.f, s1 = 0.f; \
    if ((jj) >= 2) { int m = v - 1; \
        if (m >= 0) { float sc = sIn[m] * ISCALE; \
            s0 = clip10((g0a + g0b + c0) * sc); s1 = clip10((g1a + g1b + c1) * sc); } \
        if ((jj) >= 3) { int d = d0 + DSPL + 2 - (jj); \
            *(float2*)(oR + (size_t)d * HW + w) = make_float2(s0p, s1); } } \
    s0p = s0; g0a = g0b; g0b = c0; g1a = g1b; g1b = c1; }
        LOADH(RA, vb);
#pragma unroll 2
        for (int j = 0; j < DSPL + 2; j += 2) {
            LOADH(RB, vb + j + 1);
            STEPR(RA, j);
            LOADH(RA, vb + j + 2);
            STEPR(RB, j + 1);
        }
        STEPR(RA, DSPL + 2);
#undef STEPR
    }
#undef LOADH
#undef DOTH
}

// ---------------------------------------------------------------------------
// k_e: EH[b,d,h,v] = horizontal 3-tap of E, E[v] = sum_c xl[.,v+2d]*xr[.,v].
// r7 structure + register double-buffer, unchanged EXCEPT: EH stored as fp16
// (halves the 41 MB write stream; delta_out <= ~1e-5 after norm scaling).
__global__ __launch_bounds__(448, 4) void k_e(const float* __restrict__ xl,
                                              const float* __restrict__ xr,
                                              _Float16* __restrict__ EH,
                                              float* __restrict__ sql,
                                              float* __restrict__ sqr) {
    __shared__ float sXL[W * ESTR];   // 59904 B
    int tid = threadIdx.x;
    int h = blockIdx.x;
    int b = blockIdx.y;
    int d0 = blockIdx.z * DSPL;
    int lane = tid & 63;
    int wv = tid >> 6;                // 0..6
    int v = wv * 62 + lane - 1;       // -1 .. 433
    bool vin = (v >= 0) && (v < W);
    const float* br = xr + (size_t)b * CHW + h * W;

    float xrv[C];
#pragma unroll
    for (int c = 0; c < C; ++c) xrv[c] = vin ? br[c * HW + v] : 0.0f;

    stage_row_v2(xl + (size_t)b * CHW + h * W, sXL, tid, 448);
    __syncthreads();

    bool wr = (lane >= 1) && (lane <= 62) && (v < W);   // v>=0 implied

    if (blockIdx.z == 0) {
        float sr_ = 0.f, sl_ = 0.f;
#pragma unroll
        for (int c = 0; c < C; ++c) sr_ += xrv[c] * xrv[c];
        if (vin) {
            const float4* c4 = (const float4*)(sXL + v * ESTR);
#pragma unroll
            for (int q = 0; q < 8; ++q) {
                float4 x = c4[q];
                sl_ += x.x * x.x + x.y * x.y + x.z * x.z + x.w * x.w;
            }
        }
        if (wr) {
            sqr[b * HW + h * W + v] = sr_;
            sql[b * HW + h * W + v] = sl_;
        }
    }

    _Float16* pe = EH + (((size_t)b * D) * H + h) * W + v;

    float4 RA0, RA1, RA2, RA3, RA4, RA5, RA6, RA7;
    float4 RB0, RB1, RB2, RB3, RB4, RB5, RB6, RB7;

#define LOADE(P, col) { int _vq = CLW(col); \
    const float4* _c4 = (const float4*)(sXL + (size_t)_vq * ESTR); \
    P##0 = _c4[0]; P##1 = _c4[1]; P##2 = _c4[2]; P##3 = _c4[3]; \
    P##4 = _c4[4]; P##5 = _c4[5]; P##6 = _c4[6]; P##7 = _c4[7]; }
#define STEPE(P, dd) { float _a = 0.f, _b = 0.f; \
    FMA4(_a, xrv, 0, P##0) FMA4(_a, xrv, 1, P##1) FMA4(_a, xrv, 2, P##2) FMA4(_a, xrv, 3, P##3) \
    FMA4(_b, xrv, 4, P##4) FMA4(_b, xrv, 5, P##5) FMA4(_b, xrv, 6, P##6) FMA4(_b, xrv, 7, P##7) \
    float e = (vin && (v + 2 * (dd)) < W) ? (_a + _b) : 0.f; \
    float em = __shfl_up(e, 1); \
    float ep = __shfl_down(e, 1); \
    float eh = em + e + ep; \
    if (wr) pe[(size_t)(dd) * HW] = (_Float16)eh; }

    LOADE(RA, v + 2 * d0);
#pragma unroll 2
    for (int d = d0; d < d0 + DSPL; d += 2) {
        LOADE(RB, v + 2 * d + 2);
        STEPE(RA, d);
        LOADE(RA, v + 2 * d + 4);
        STEPE(RB, d + 1);
    }
#undef LOADE
#undef STEPE
}

// ---------------------------------------------------------------------------
// k_lr2: sLR = vertical 3-tap of fp16 EH at column vc=w-d, times inverse
// norms. (r1-measured-good grid (4,H,B).)
#define DCH 12
__global__ __launch_bounds__(448) void k_lr2(const _Float16* __restrict__ EH,
                                             const float* __restrict__ inl,
                                             const float* __restrict__ inr,
                                             float* __restrict__ out) {
    int w = threadIdx.x;
    int dc = blockIdx.x;              // 0..3
    int h = blockIdx.y;
    int b = blockIdx.z;
    if (w >= W) return;
    int bhw = b * HW + h * W;
    bool hm = (h > 0), hp = (h < H - 1);

    float* o = out + ((size_t)b * 3 + 2) * D * HW + h * W + w;
#pragma unroll
    for (int i = 0; i < DCH; ++i) {
        int d = dc * DCH + i;
        float r = 0.0f;
        if (w >= d && w + d < W) {
            int vc = w - d;
            const _Float16* base = EH + ((size_t)b * D + d) * HW + vc;
            float e = (float)base[h * W];
            if (hm) e += (float)base[(h - 1) * W];
            if (hp) e += (float)base[(h + 1) * W];
            float nl = inl[bhw + w + d];
            float nr = inr[bhw + vc];
            r = clip10(e * nl * nr * ISCALE);
        }
        o[(size_t)d * HW] = r;
    }
}

// ---------------------------------------------------------------------------
extern "C" void kernel_launch(void* const* d_in, const int* in_sizes, int n_in,
                              void* d_out, int out_size, void* d_ws, size_t ws_size,
                              hipStream_t stream) {
    const float* xl = (const float*)d_in[0];
    const float* xm = (const float*)d_in[1];
    const float* xr = (const float*)d_in[2];
    float* out = (float*)d_out;

    float* ws = (float*)d_ws;
    float* inl = ws;                               // B*HW
    float* inr = inl + B * HW;                     // B*HW
    float* sql = inr + B * HW;                     // B*HW
    float* sqr = sql + B * HW;                     // B*HW
    _Float16* EH = (_Float16*)(sqr + B * HW);      // B*D*H*W halfs

    k_e<<<dim3(H, B, 2), dim3(448), 0, stream>>>(xl, xr, EH, sql, sqr);
    k_norm<<<dim3((B * HW + 255) / 256), dim3(256), 0, stream>>>(sql, sqr, inl, inr);
    k_lr<<<dim3(H, B, 2), dim3(256), 0, stream>>>(xm, xl, xr, inl, inr, out);
    k_lr2<<<dim3(4, H, B), dim3(448), 0, stream>>>(EH, inl, inr, out);
}

// Round 12
// 161.925 us; speedup vs baseline: 1.2072x; 1.0148x over previous
//
#include <hip/hip_runtime.h>
#include <math.h>

#define B 2
#define C 32
#define H 128
#define W 416
#define D 48
#define HW (H*W)
#define CHW (C*HW)
#define EPSN 1e-3f
#define ISCALE 0.05892556509887896f   // 1/sqrt(C*9)
#define ESTR 36     // k_e LDS stride (floats): stride-1 reads conflict-free
#define DSPL (D / 2)                   // disparities per z-block (24)

typedef _Float16 h16;
typedef _Float16 __attribute__((ext_vector_type(2))) h16x2;

__device__ __forceinline__ float clip10(float x) {
    return fminf(fmaxf(x, -10.0f), 10.0f);
}

__device__ __forceinline__ float fdot2(h16x2 a, h16x2 bb, float c) {
    return __builtin_amdgcn_fdot2(a, bb, c, false);
}
__device__ __forceinline__ h16x2 u2h(unsigned int u) {
    union { unsigned int u; h16x2 h; } cv; cv.u = u; return cv.h;
}
__device__ __forceinline__ unsigned int pkh(float a, float bb) {
    union { h16x2 h; unsigned int u; } cv;
    cv.h = h16x2{(h16)a, (h16)bb}; return cv.u;
}

#define FMA4(acc, f, k, u) acc += f[4*(k)+0]*(u).x + f[4*(k)+1]*(u).y \
                               + f[4*(k)+2]*(u).z + f[4*(k)+3]*(u).w;

#define CLW(v) ((v) < 0 ? 0 : ((v) > (W - 1) ? (W - 1) : (v)))

// ---------------------------------------------------------------------------
// k_norm: 3x3 zero-padded box of sql/sqr -> inverse patch norms inl/inr.
__global__ __launch_bounds__(256) void k_norm(const float* __restrict__ sql,
                                              const float* __restrict__ sqr,
                                              float* __restrict__ inl,
                                              float* __restrict__ inr) {
    int idx = blockIdx.x * 256 + threadIdx.x;
    if (idx >= B * HW) return;
    int b = idx / HW, hw = idx - b * HW;
    int h = hw / W, w = hw - h * W;
    float sl = 0.f, sr = 0.f;
#pragma unroll
    for (int di = -1; di <= 1; ++di) {
        int hh = h + di;
        if (hh < 0 || hh >= H) continue;
#pragma unroll
        for (int dj = -1; dj <= 1; ++dj) {
            int ww = w + dj;
            if (ww < 0 || ww >= W) continue;
            int p = b * HW + hh * W + ww;
            sl += sql[p];
            sr += sqr[p];
        }
    }
    inl[idx] = 1.0f / fmaxf(sqrtf(sl), EPSN);
    inr[idx] = 1.0f / fmaxf(sqrtf(sr), EPSN);
}

// ---------------------------------------------------------------------------
// stage_row_v2 (k_e): stage [C][W] row into LDS transposed [w][c], stride
// ESTR=36 (fp32, unchanged r7-good).
__device__ __forceinline__ void stage_row_v2(const float* __restrict__ gsrc,
                                             float* __restrict__ lds,
                                             int tid, int nthreads) {
    for (int t = tid; t < (W / 4) * C; t += nthreads) {
        int rw = t & 7;
        int cl = (t >> 3) & 7;
        int g  = t >> 6;              // 0..51
        int wg = g % 13;
        int ch = g / 13;              // 0..3
        int c  = ch * 8 + cl;
        int w4 = (wg * 8 + rw) * 4;
        float4 v = *(const float4*)(gsrc + (size_t)c * HW + w4);
        lds[(w4 + 0) * ESTR + c] = v.x;
        lds[(w4 + 1) * ESTR + c] = v.y;
        lds[(w4 + 2) * ESTR + c] = v.z;
        lds[(w4 + 3) * ESTR + c] = v.w;
    }
}

// ---------------------------------------------------------------------------
// stage_row3_h (k_lr): stage VERTICAL 3-tap vsum as PACKED fp16 channel-pairs.
// Column v = 16 dwords, 64 B. Layout:
//   base dword  = 16 * (v ^ ((v>>1)&1))
//   phys dword  = 4*((dw>>2) ^ ky(v)) + (dw&3),  ky(v) = ((v>>1)^(v>>2))&3
// Reads (v = v0+2*lane): all 32 banks, 8 dwords/bank = structural min.
// Writes: 4-way on half the instructions ~ net free.
__device__ __forceinline__ void stage_row3_h(const float* __restrict__ gsrc,
                                             unsigned int* __restrict__ lds,
                                             int h, int tid, int nthreads) {
    for (int t = tid; t < (W / 4) * (C / 2); t += nthreads) {   // 1664 items
        int p = t & 15;               // channel pair 0..15
        int u = t >> 4;               // column quad 0..103
        int v0 = 4 * u;
        const float* pa = gsrc + (size_t)(2 * p) * HW + v0;
        const float* pb = pa + HW;
        float4 va = *(const float4*)pa;
        float4 vb = *(const float4*)pb;
        if (h > 0) {
            float4 xa = *(const float4*)(pa - W);
            float4 xb = *(const float4*)(pb - W);
            va.x += xa.x; va.y += xa.y; va.z += xa.z; va.w += xa.w;
            vb.x += xb.x; vb.y += xb.y; vb.z += xb.z; vb.w += xb.w;
        }
        if (h < H - 1) {
            float4 xa = *(const float4*)(pa + W);
            float4 xb = *(const float4*)(pb + W);
            va.x += xa.x; va.y += xa.y; va.z += xa.z; va.w += xa.w;
            vb.x += xb.x; vb.y += xb.y; vb.z += xb.z; vb.w += xb.w;
        }
        int q = p >> 2, lo = p & 3;
        unsigned int pk0 = pkh(va.x, vb.x);
        unsigned int pk1 = pkh(va.y, vb.y);
        unsigned int pk2 = pkh(va.z, vb.z);
        unsigned int pk3 = pkh(va.w, vb.w);
#define PUTH(vv, val) { int _v = (vv); \
    lds[16 * (_v ^ ((_v >> 1) & 1)) \
        + 4 * (q ^ ((((_v) >> 1) ^ ((_v) >> 2)) & 3)) + lo] = (val); }
        PUTH(v0 + 0, pk0)
        PUTH(v0 + 1, pk1)
        PUTH(v0 + 2, pk2)
        PUTH(v0 + 3, pk3)
#undef PUTH
    }
}

// ---------------------------------------------------------------------------
// dot32e (k_e): 8 b128 loads issued up front, 2 independent FMA chains.
__device__ __forceinline__ float dot32e(const float* __restrict__ x,
                                        const float* __restrict__ col) {
    const float4* c4 = (const float4*)col;
    float4 u0 = c4[0], u1 = c4[1], u2 = c4[2], u3 = c4[3];
    float4 u4 = c4[4], u5 = c4[5], u6 = c4[6], u7 = c4[7];
    float a = 0.f, bb = 0.f;
    FMA4(a, x, 0, u0) FMA4(a, x, 1, u1) FMA4(a, x, 2, u2) FMA4(a, x, 3, u3)
    FMA4(bb, x, 4, u4) FMA4(bb, x, 5, u5) FMA4(bb, x, 6, u6) FMA4(bb, x, 7, u7)
    return a + bb;
}

// ---------------------------------------------------------------------------
// k_lr: sL and sR fused into one 512-thread block (8 waves): waves 0-3 run
// the L dot-loop, waves 4-7 run R CONCURRENTLY (both tiles staged once).
// Doubles waves/CU 8 -> 16 (4/SIMD) with zero extra HBM traffic — k_lr was
// latency-bound at 2 waves/SIMD (r11: halving LDS+VALU pipes moved dur by
// only 5%). fp16 tile + v_dot2, register double-buffer as r11.
__global__ __launch_bounds__(512) void k_lr(const float* __restrict__ xm,
                                            const float* __restrict__ xl,
                                            const float* __restrict__ xr,
                                            const float* __restrict__ inl,
                                            const float* __restrict__ inr,
                                            float* __restrict__ out) {
    __shared__ unsigned int sBuL[W * 16];   // 26624 B
    __shared__ unsigned int sBuR[W * 16];   // 26624 B
    __shared__ float sInL[W];               // 1664 B
    __shared__ float sInR[W];               // 1664 B
    int tid = threadIdx.x;
    int grp = tid >> 8;               // 0 = phase L, 1 = phase R
    int t8 = tid & 255;
    int h = blockIdx.x;
    int b = blockIdx.y;
    int d0 = blockIdx.z * DSPL;
    bool act = t8 < (W / 2);          // 208 active per group
    int w = 2 * t8;
    int bhw = b * HW + h * W;
    const float* pm = xm + (size_t)b * CHW + h * W;

    // fl for w and w+1, normalized, packed to fp16 channel-pairs.
    // (L and R groups load the same xm values; second read is an L1/L2 hit.)
    h16x2 f0h[16], f1h[16];
    if (act) {
        float t0[C], t1[C];
        float am0 = 0.f, am1 = 0.f;
#pragma unroll
        for (int c = 0; c < C; ++c) {
            float2 mv = *(const float2*)(pm + (size_t)c * HW + w);
            t0[c] = mv.x; t1[c] = mv.y;
            am0 += mv.x * mv.x; am1 += mv.y * mv.y;
        }
        float im0 = 1.0f / fmaxf(sqrtf(am0), EPSN);
        float im1 = 1.0f / fmaxf(sqrtf(am1), EPSN);
#pragma unroll
        for (int j = 0; j < 16; ++j) {
            f0h[j] = h16x2{(h16)(t0[2 * j] * im0), (h16)(t0[2 * j + 1] * im0)};
            f1h[j] = h16x2{(h16)(t1[2 * j] * im1), (h16)(t1[2 * j + 1] * im1)};
        }
    } else {
#pragma unroll
        for (int j = 0; j < 16; ++j) { f0h[j] = h16x2{(h16)0.f, (h16)0.f};
                                       f1h[j] = h16x2{(h16)0.f, (h16)0.f}; }
    }

    // Stage BOTH tiles with all 512 threads, single barrier.
    stage_row3_h(xl + (size_t)b * CHW + h * W, sBuL, h, tid, 512);
    stage_row3_h(xr + (size_t)b * CHW + h * W, sBuR, h, tid, 512);
    for (int j = tid; j < W; j += 512) {
        sInL[j] = inl[bhw + j];
        sInR[j] = inr[bhw + j];
    }
    __syncthreads();

    uint4 RA0, RA1, RA2, RA3;
    uint4 RB0, RB1, RB2, RB3;

#define LOADH(P, buf, vv) { int _v = CLW(vv); \
    const uint4* _c4 = (const uint4*)((buf) + 16 * (_v ^ ((_v >> 1) & 1))); \
    int _ky = ((_v >> 1) ^ (_v >> 2)) & 3; \
    P##0 = _c4[_ky]; P##1 = _c4[1 ^ _ky]; P##2 = _c4[2 ^ _ky]; P##3 = _c4[3 ^ _ky]; }

#define DOTH(P, c0, c1) { \
    float _a0 = 0.f, _a1 = 0.f, _b0 = 0.f, _b1 = 0.f; \
    _a0 = fdot2(f0h[0],  u2h((P##0).x), _a0); _a0 = fdot2(f0h[1],  u2h((P##0).y), _a0); \
    _a0 = fdot2(f0h[2],  u2h((P##0).z), _a0); _a0 = fdot2(f0h[3],  u2h((P##0).w), _a0); \
    _a0 = fdot2(f0h[4],  u2h((P##1).x), _a0); _a0 = fdot2(f0h[5],  u2h((P##1).y), _a0); \
    _a0 = fdot2(f0h[6],  u2h((P##1).z), _a0); _a0 = fdot2(f0h[7],  u2h((P##1).w), _a0); \
    _a1 = fdot2(f0h[8],  u2h((P##2).x), _a1); _a1 = fdot2(f0h[9],  u2h((P##2).y), _a1); \
    _a1 = fdot2(f0h[10], u2h((P##2).z), _a1); _a1 = fdot2(f0h[11], u2h((P##2).w), _a1); \
    _a1 = fdot2(f0h[12], u2h((P##3).x), _a1); _a1 = fdot2(f0h[13], u2h((P##3).y), _a1); \
    _a1 = fdot2(f0h[14], u2h((P##3).z), _a1); _a1 = fdot2(f0h[15], u2h((P##3).w), _a1); \
    _b0 = fdot2(f1h[0],  u2h((P##0).x), _b0); _b0 = fdot2(f1h[1],  u2h((P##0).y), _b0); \
    _b0 = fdot2(f1h[2],  u2h((P##0).z), _b0); _b0 = fdot2(f1h[3],  u2h((P##0).w), _b0); \
    _b0 = fdot2(f1h[4],  u2h((P##1).x), _b0); _b0 = fdot2(f1h[5],  u2h((P##1).y), _b0); \
    _b0 = fdot2(f1h[6],  u2h((P##1).z), _b0); _b0 = fdot2(f1h[7],  u2h((P##1).w), _b0); \
    _b1 = fdot2(f1h[8],  u2h((P##2).x), _b1); _b1 = fdot2(f1h[9],  u2h((P##2).y), _b1); \
    _b1 = fdot2(f1h[10], u2h((P##2).z), _b1); _b1 = fdot2(f1h[11], u2h((P##2).w), _b1); \
    _b1 = fdot2(f1h[12], u2h((P##3).x), _b1); _b1 = fdot2(f1h[13], u2h((P##3).y), _b1); \
    _b1 = fdot2(f1h[14], u2h((P##3).z), _b1); _b1 = fdot2(f1h[15], u2h((P##3).w), _b1); \
    c0 = _a0 + _a1; c1 = _b0 + _b1; }

    if (act && grp == 0) {
        // ---- phase L: columns v = w+d0-1+j, j=0..26. Center m=v-1 done at
        // j>=2; store pairs (s0 from j-1, s1 from j) at j>=3, d = d0+j-3.
        float* oL = out + ((size_t)b * 3 + 0) * D * HW + h * W;
        const int vb = w + d0 - 1;
        float g0a = 0.f, g0b = 0.f, g1a = 0.f, g1b = 0.f, s0p = 0.f;
#define STEPL(P, jj) { int v = vb + (jj); bool ok = (v >= 0) && (v < W); \
    float c0, c1; DOTH(P, c0, c1); c0 = ok ? c0 : 0.f; c1 = ok ? c1 : 0.f; \
    float s0 = 0.f, s1 = 0.f; \
    if ((jj) >= 2) { int m = v - 1; \
        if (m < W) { float sc = sInL[m] * ISCALE; \
            s0 = clip10((g0a + g0b + c0) * sc); s1 = clip10((g1a + g1b + c1) * sc); } \
        if ((jj) >= 3) { int d = d0 + (jj) - 3; \
            *(float2*)(oL + (size_t)d * HW + w) = make_float2(s0p, s1); } } \
    s0p = s0; g0a = g0b; g0b = c0; g1a = g1b; g1b = c1; }
        LOADH(RA, sBuL, vb);
#pragma unroll 2
        for (int j = 0; j < DSPL + 2; j += 2) {   // steps 0..25; tail 26
            LOADH(RB, sBuL, vb + j + 1);
            STEPL(RA, j);
            LOADH(RA, sBuL, vb + j + 2);
            STEPL(RB, j + 1);
        }
        STEPL(RA, DSPL + 2);
#undef STEPL
    } else if (act) {
        // ---- phase R: columns v = w-d0-DSPL+j, j=0..26, ascending. Center
        // m=v-1 at j>=2; store pairs at j>=3 for d = d0+DSPL+2-j.
        float* oR = out + ((size_t)b * 3 + 1) * D * HW + h * W;
        const int vb = w - d0 - DSPL;
        float g0a = 0.f, g0b = 0.f, g1a = 0.f, g1b = 0.f, s0p = 0.f;
#define STEPR(P, jj) { int v = vb + (jj); bool ok = (v >= 0) && (v < W); \
    float c0, c1; DOTH(P, c0, c1); c0 = ok ? c0 : 0.f; c1 = ok ? c1 : 0.f; \
    float s0 = 0.f, s1 = 0.f; \
    if ((jj) >= 2) { int m = v - 1; \
        if (m >= 0) { float sc = sInR[m] * ISCALE; \
            s0 = clip10((g0a + g0b + c0) * sc); s1 = clip10((g1a + g1b + c1) * sc); } \
        if ((jj) >= 3) { int d = d0 + DSPL + 2 - (jj); \
            *(float2*)(oR + (size_t)d * HW + w) = make_float2(s0p, s1); } } \
    s0p = s0; g0a = g0b; g0b = c0; g1a = g1b; g1b = c1; }
        LOADH(RA, sBuR, vb);
#pragma unroll 2
        for (int j = 0; j < DSPL + 2; j += 2) {
            LOADH(RB, sBuR, vb + j + 1);
            STEPR(RA, j);
            LOADH(RA, sBuR, vb + j + 2);
            STEPR(RB, j + 1);
        }
        STEPR(RA, DSPL + 2);
#undef STEPR
    }
#undef LOADH
#undef DOTH
}

// ---------------------------------------------------------------------------
// k_e: EH[b,d,h,v] = horizontal 3-tap of E, E[v] = sum_c xl[.,v+2d]*xr[.,v].
// r7 structure + register double-buffer; EH stored fp16.
__global__ __launch_bounds__(448, 4) void k_e(const float* __restrict__ xl,
                                              const float* __restrict__ xr,
                                              _Float16* __restrict__ EH,
                                              float* __restrict__ sql,
                                              float* __restrict__ sqr) {
    __shared__ float sXL[W * ESTR];   // 59904 B
    int tid = threadIdx.x;
    int h = blockIdx.x;
    int b = blockIdx.y;
    int d0 = blockIdx.z * DSPL;
    int lane = tid & 63;
    int wv = tid >> 6;                // 0..6
    int v = wv * 62 + lane - 1;       // -1 .. 433
    bool vin = (v >= 0) && (v < W);
    const float* br = xr + (size_t)b * CHW + h * W;

    float xrv[C];
#pragma unroll
    for (int c = 0; c < C; ++c) xrv[c] = vin ? br[c * HW + v] : 0.0f;

    stage_row_v2(xl + (size_t)b * CHW + h * W, sXL, tid, 448);
    __syncthreads();

    bool wr = (lane >= 1) && (lane <= 62) && (v < W);   // v>=0 implied

    if (blockIdx.z == 0) {
        float sr_ = 0.f, sl_ = 0.f;
#pragma unroll
        for (int c = 0; c < C; ++c) sr_ += xrv[c] * xrv[c];
        if (vin) {
            const float4* c4 = (const float4*)(sXL + v * ESTR);
#pragma unroll
            for (int q = 0; q < 8; ++q) {
                float4 x = c4[q];
                sl_ += x.x * x.x + x.y * x.y + x.z * x.z + x.w * x.w;
            }
        }
        if (wr) {
            sqr[b * HW + h * W + v] = sr_;
            sql[b * HW + h * W + v] = sl_;
        }
    }

    _Float16* pe = EH + (((size_t)b * D) * H + h) * W + v;

    float4 RA0, RA1, RA2, RA3, RA4, RA5, RA6, RA7;
    float4 RB0, RB1, RB2, RB3, RB4, RB5, RB6, RB7;

#define LOADE(P, col) { int _vq = CLW(col); \
    const float4* _c4 = (const float4*)(sXL + (size_t)_vq * ESTR); \
    P##0 = _c4[0]; P##1 = _c4[1]; P##2 = _c4[2]; P##3 = _c4[3]; \
    P##4 = _c4[4]; P##5 = _c4[5]; P##6 = _c4[6]; P##7 = _c4[7]; }
#define STEPE(P, dd) { float _a = 0.f, _b = 0.f; \
    FMA4(_a, xrv, 0, P##0) FMA4(_a, xrv, 1, P##1) FMA4(_a, xrv, 2, P##2) FMA4(_a, xrv, 3, P##3) \
    FMA4(_b, xrv, 4, P##4) FMA4(_b, xrv, 5, P##5) FMA4(_b, xrv, 6, P##6) FMA4(_b, xrv, 7, P##7) \
    float e = (vin && (v + 2 * (dd)) < W) ? (_a + _b) : 0.f; \
    float em = __shfl_up(e, 1); \
    float ep = __shfl_down(e, 1); \
    float eh = em + e + ep; \
    if (wr) pe[(size_t)(dd) * HW] = (_Float16)eh; }

    LOADE(RA, v + 2 * d0);
#pragma unroll 2
    for (int d = d0; d < d0 + DSPL; d += 2) {
        LOADE(RB, v + 2 * d + 2);
        STEPE(RA, d);
        LOADE(RA, v + 2 * d + 4);
        STEPE(RB, d + 1);
    }
#undef LOADE
#undef STEPE
}

// ---------------------------------------------------------------------------
// k_lr2: sLR = vertical 3-tap of fp16 EH at column vc=w-d, times inverse
// norms. (r1-measured-good grid (4,H,B).)
#define DCH 12
__global__ __launch_bounds__(448) void k_lr2(const _Float16* __restrict__ EH,
                                             const float* __restrict__ inl,
                                             const float* __restrict__ inr,
                                             float* __restrict__ out) {
    int w = threadIdx.x;
    int dc = blockIdx.x;              // 0..3
    int h = blockIdx.y;
    int b = blockIdx.z;
    if (w >= W) return;
    int bhw = b * HW + h * W;
    bool hm = (h > 0), hp = (h < H - 1);

    float* o = out + ((size_t)b * 3 + 2) * D * HW + h * W + w;
#pragma unroll
    for (int i = 0; i < DCH; ++i) {
        int d = dc * DCH + i;
        float r = 0.0f;
        if (w >= d && w + d < W) {
            int vc = w - d;
            const _Float16* base = EH + ((size_t)b * D + d) * HW + vc;
            float e = (float)base[h * W];
            if (hm) e += (float)base[(h - 1) * W];
            if (hp) e += (float)base[(h + 1) * W];
            float nl = inl[bhw + w + d];
            float nr = inr[bhw + vc];
            r = clip10(e * nl * nr * ISCALE);
        }
        o[(size_t)d * HW] = r;
    }
}

// ---------------------------------------------------------------------------
extern "C" void kernel_launch(void* const* d_in, const int* in_sizes, int n_in,
                              void* d_out, int out_size, void* d_ws, size_t ws_size,
                              hipStream_t stream) {
    const float* xl = (const float*)d_in[0];
    const float* xm = (const float*)d_in[1];
    const float* xr = (const float*)d_in[2];
    float* out = (float*)d_out;

    float* ws = (float*)d_ws;
    float* inl = ws;                               // B*HW
    float* inr = inl + B * HW;                     // B*HW
    float* sql = inr + B * HW;                     // B*HW
    float* sqr = sql + B * HW;                     // B*HW
    _Float16* EH = (_Float16*)(sqr + B * HW);      // B*D*H*W halfs

    k_e<<<dim3(H, B, 2), dim3(448), 0, stream>>>(xl, xr, EH, sql, sqr);
    k_norm<<<dim3((B * HW + 255) / 256), dim3(256), 0, stream>>>(sql, sqr, inl, inr);
    k_lr<<<dim3(H, B, 2), dim3(512), 0, stream>>>(xm, xl, xr, inl, inr, out);
    k_lr2<<<dim3(4, H, B), dim3(448), 0, stream>>>(EH, inl, inr, out);
}